// Round 1
// baseline (524.887 us; speedup 1.0000x reference)
//
#include <hip/hip_runtime.h>
#include <hip/hip_bf16.h>

typedef __bf16 bf16_t;
typedef __bf16 bf16x2 __attribute__((ext_vector_type(2)));
typedef __bf16 bf16x8 __attribute__((ext_vector_type(8)));
typedef float floatx4 __attribute__((ext_vector_type(4)));

#define NTOK 73728   // 8*96*96

// ---------------- weight transpose + bf16 convert: out[n*K+k] = in[k*N+n]
__global__ void kconv_t(const float* __restrict__ in, bf16_t* __restrict__ out, int K, int N) {
    int idx = blockIdx.x * 256 + threadIdx.x;
    if (idx >= K * N) return;
    int n = idx / K, k = idx - n * K;
    out[idx] = (bf16_t)in[k * N + n];
}

// ---------------- LayerNorm over 128 channels, fp32 in -> bf16 out (wave per row)
__global__ __launch_bounds__(256) void kln128(const float* __restrict__ x, const float* __restrict__ g,
                                              const float* __restrict__ bta, bf16_t* __restrict__ out, int M) {
    int row = blockIdx.x * 4 + (threadIdx.x >> 6);
    int lane = threadIdx.x & 63;
    if (row >= M) return;
    float2 v = *(const float2*)&x[row * 128 + lane * 2];
    float s = v.x + v.y;
    float sq = v.x * v.x + v.y * v.y;
    #pragma unroll
    for (int d = 1; d < 64; d <<= 1) { s += __shfl_xor(s, d, 64); sq += __shfl_xor(sq, d, 64); }
    float m = s * (1.0f / 128.0f);
    float var = sq * (1.0f / 128.0f) - m * m;
    float inv = 1.0f / sqrtf(var + 1e-5f);
    float2 gg = *(const float2*)&g[lane * 2];
    float2 bb = *(const float2*)&bta[lane * 2];
    bf16x2 o;
    o[0] = (bf16_t)((v.x - m) * inv * gg.x + bb.x);
    o[1] = (bf16_t)((v.y - m) * inv * gg.y + bb.y);
    *(bf16x2*)&out[row * 128 + lane * 2] = o;
}

// ---------------- patch-merge gather + LayerNorm over 512 -> bf16 (wave per output row)
__global__ __launch_bounds__(256) void kmergeln(const float* __restrict__ x, const float* __restrict__ g,
                                                const float* __restrict__ bta, bf16_t* __restrict__ out) {
    int row = blockIdx.x * 4 + (threadIdx.x >> 6);   // 0..18431
    int lane = threadIdx.x & 63;
    int b = row / 2304; int rr = row - b * 2304;
    int i2 = rr / 48, j2 = rr - i2 * 48;
    int q = lane >> 4;               // concat quadrant: 0:(0,0) 1:(1,0) 2:(0,1) 3:(1,1)
    int cc = (lane & 15) * 8;        // channel within 128
    int di = q & 1, dj = q >> 1;
    int src = ((b * 96 + i2 * 2 + di) * 96 + (j2 * 2 + dj)) * 128 + cc;
    float4 a0 = *(const float4*)&x[src];
    float4 a1 = *(const float4*)&x[src + 4];
    float s  = a0.x + a0.y + a0.z + a0.w + a1.x + a1.y + a1.z + a1.w;
    float sq = a0.x*a0.x + a0.y*a0.y + a0.z*a0.z + a0.w*a0.w
             + a1.x*a1.x + a1.y*a1.y + a1.z*a1.z + a1.w*a1.w;
    #pragma unroll
    for (int d = 1; d < 64; d <<= 1) { s += __shfl_xor(s, d, 64); sq += __shfl_xor(sq, d, 64); }
    float m = s * (1.0f / 512.0f);
    float var = sq * (1.0f / 512.0f) - m * m;
    float inv = 1.0f / sqrtf(var + 1e-5f);
    int c = q * 128 + cc;
    float4 g0 = *(const float4*)&g[c];
    float4 g1 = *(const float4*)&g[c + 4];
    float4 b0 = *(const float4*)&bta[c];
    float4 b1 = *(const float4*)&bta[c + 4];
    bf16x8 o;
    o[0] = (bf16_t)((a0.x - m) * inv * g0.x + b0.x);
    o[1] = (bf16_t)((a0.y - m) * inv * g0.y + b0.y);
    o[2] = (bf16_t)((a0.z - m) * inv * g0.z + b0.z);
    o[3] = (bf16_t)((a0.w - m) * inv * g0.w + b0.w);
    o[4] = (bf16_t)((a1.x - m) * inv * g1.x + b1.x);
    o[5] = (bf16_t)((a1.y - m) * inv * g1.y + b1.y);
    o[6] = (bf16_t)((a1.z - m) * inv * g1.z + b1.z);
    o[7] = (bf16_t)((a1.w - m) * inv * g1.w + b1.w);
    *(bf16x8*)&out[row * 512 + c] = o;
}

// ---------------- GEMM: out(M,N) = A(M,K) @ Bt(N,K)^T (+bias)(+res)(gelu)
// MODE 0: bf16 out = acc+bias   (qkv)
// MODE 1: f32 out = res + acc + bias  (proj / fc2, residual)
// MODE 2: bf16 out = gelu(acc+bias)   (fc1)
// MODE 3: f32 out = acc               (patch-merge reduction)
template<int MODE>
__global__ __launch_bounds__(256) void gemm64(const bf16_t* __restrict__ A,
                                              const bf16_t* __restrict__ Bt,
                                              const float* __restrict__ bias,
                                              const float* __restrict__ res,
                                              float* __restrict__ outf,
                                              bf16_t* __restrict__ outh,
                                              int M, int N, int K) {
    alignas(16) __shared__ bf16_t lA[64 * 32];
    alignas(16) __shared__ bf16_t lB[64 * 32];
    const int tid = threadIdx.x;
    const int lane = tid & 63;
    const int wv = tid >> 6;
    const int wm = (wv & 1) * 32, wn = (wv >> 1) * 32;
    const int frow = lane & 15, fk = (lane >> 4) * 8;
    const int rowA = blockIdx.y * 64;
    const int rowB = blockIdx.x * 64;
    const int srow = tid >> 2, scol = (tid & 3) * 8;
    floatx4 acc[2][2] = {};
    const bf16_t* pa = A + (size_t)(rowA + srow) * K + scol;
    const bf16_t* pb = Bt + (size_t)(rowB + srow) * K + scol;
    for (int k0 = 0; k0 < K; k0 += 32) {
        __syncthreads();
        *(uint4*)&lA[srow * 32 + scol] = *(const uint4*)(pa + k0);
        *(uint4*)&lB[srow * 32 + scol] = *(const uint4*)(pb + k0);
        __syncthreads();
        bf16x8 af[2], bf[2];
        af[0] = *(const bf16x8*)&lA[(wm + frow) * 32 + fk];
        af[1] = *(const bf16x8*)&lA[(wm + 16 + frow) * 32 + fk];
        bf[0] = *(const bf16x8*)&lB[(wn + frow) * 32 + fk];
        bf[1] = *(const bf16x8*)&lB[(wn + 16 + frow) * 32 + fk];
        #pragma unroll
        for (int i = 0; i < 2; i++)
            #pragma unroll
            for (int j = 0; j < 2; j++)
                acc[i][j] = __builtin_amdgcn_mfma_f32_16x16x32_bf16(af[i], bf[j], acc[i][j], 0, 0, 0);
    }
    #pragma unroll
    for (int i = 0; i < 2; i++) {
        #pragma unroll
        for (int j = 0; j < 2; j++) {
            int col = rowB + wn + j * 16 + frow;
            float bs = (MODE == 3) ? 0.0f : bias[col];
            #pragma unroll
            for (int r = 0; r < 4; r++) {
                int row = rowA + wm + i * 16 + (lane >> 4) * 4 + r;
                float v = acc[i][j][r] + bs;
                size_t off = (size_t)row * N + col;
                if (MODE == 0) {
                    outh[off] = (bf16_t)v;
                } else if (MODE == 1) {
                    outf[off] = res[off] + v;
                } else if (MODE == 2) {
                    outh[off] = (bf16_t)(0.5f * v * (1.0f + erff(v * 0.70710678118654752f)));
                } else {
                    outf[off] = v;
                }
            }
        }
    }
}

// ---------------- fused window attention: one wave per (window, head)
// qkv: (NTOK, 384) bf16, token rows in original (b,i,j) layout; q|k|v each 4 heads * 32
// out: (NTOK, 128) bf16 attention output (window-reverse + roll-back folded into indexing)
__global__ __launch_bounds__(64) void kattn(const bf16_t* __restrict__ qkv, bf16_t* __restrict__ out, int shift) {
    alignas(16) __shared__ bf16_t lp[64 * 64];  // P matrix, [query][key]
    alignas(16) __shared__ bf16_t lv[64 * 32];  // V, [key][feat]
    int blk = blockIdx.x;
    int win = blk >> 2, h = blk & 3;
    int b = win / 144; int wr = win - b * 144;
    int wi = wr / 12, wj = wr - wi * 12;
    int ri0 = wi * 8, rj0 = wj * 8;
    int lane = threadIdx.x;
    auto trow = [&](int n) {
        int oi = ri0 + (n >> 3) + shift; oi = (oi >= 96) ? oi - 96 : oi;
        int oj = rj0 + (n & 7) + shift;  oj = (oj >= 96) ? oj - 96 : oj;
        return (b * 96 + oi) * 96 + oj;
    };
    // stage V: each lane copies its own token's v row (32 bf16)
    {
        size_t base = (size_t)trow(lane) * 384 + 256 + h * 32;
        *(uint4*)&lv[lane * 32]      = *(const uint4*)&qkv[base];
        *(uint4*)&lv[lane * 32 + 8]  = *(const uint4*)&qkv[base + 8];
        *(uint4*)&lv[lane * 32 + 16] = *(const uint4*)&qkv[base + 16];
        *(uint4*)&lv[lane * 32 + 24] = *(const uint4*)&qkv[base + 24];
    }
    int frow = lane & 15, fk = (lane >> 4) * 8;
    // Q, K fragments straight from global (16B contiguous per lane)
    bf16x8 qf[4], kf[4];
    #pragma unroll
    for (int t = 0; t < 4; t++) {
        size_t rq = (size_t)trow(t * 16 + frow) * 384;
        qf[t] = *(const bf16x8*)&qkv[rq + h * 32 + fk];
        kf[t] = *(const bf16x8*)&qkv[rq + 128 + h * 32 + fk];
    }
    floatx4 S[4][4] = {};
    #pragma unroll
    for (int mt = 0; mt < 4; mt++)
        #pragma unroll
        for (int nt = 0; nt < 4; nt++)
            S[mt][nt] = __builtin_amdgcn_mfma_f32_16x16x32_bf16(qf[mt], kf[nt], S[mt][nt], 0, 0, 0);
    const float scale = 0.17677669529663687f;  // 32^-0.5
    #pragma unroll
    for (int mt = 0; mt < 4; mt++)
        #pragma unroll
        for (int nt = 0; nt < 4; nt++)
            #pragma unroll
            for (int r = 0; r < 4; r++) S[mt][nt][r] *= scale;
    if (shift > 0) {
        auto grpn = [&](int n) {
            int ri = ri0 + (n >> 3), rj = rj0 + (n & 7);
            int gr = (ri < 88) ? 0 : ((ri < 92) ? 1 : 2);
            int gc = (rj < 88) ? 0 : ((rj < 92) ? 1 : 2);
            return gr * 3 + gc;
        };
        int gk[4];
        #pragma unroll
        for (int nt = 0; nt < 4; nt++) gk[nt] = grpn(nt * 16 + frow);
        #pragma unroll
        for (int mt = 0; mt < 4; mt++)
            #pragma unroll
            for (int r = 0; r < 4; r++) {
                int gq = grpn(mt * 16 + (lane >> 4) * 4 + r);
                #pragma unroll
                for (int nt = 0; nt < 4; nt++)
                    if (gq != gk[nt]) S[mt][nt][r] = -1e30f;
            }
    }
    // softmax per query row (row is spread over the 16 lanes sharing lane>>4, 4 cols each)
    #pragma unroll
    for (int mt = 0; mt < 4; mt++) {
        #pragma unroll
        for (int r = 0; r < 4; r++) {
            float mx = fmaxf(fmaxf(S[mt][0][r], S[mt][1][r]), fmaxf(S[mt][2][r], S[mt][3][r]));
            #pragma unroll
            for (int d = 1; d < 16; d <<= 1) mx = fmaxf(mx, __shfl_xor(mx, d, 64));
            float sm = 0.0f;
            #pragma unroll
            for (int nt = 0; nt < 4; nt++) {
                float p = __expf(S[mt][nt][r] - mx);
                S[mt][nt][r] = p;
                sm += p;
            }
            #pragma unroll
            for (int d = 1; d < 16; d <<= 1) sm += __shfl_xor(sm, d, 64);
            float inv = 1.0f / sm;
            #pragma unroll
            for (int nt = 0; nt < 4; nt++) S[mt][nt][r] *= inv;
        }
    }
    // P -> LDS (C-layout scatter), then re-read in A-layout
    #pragma unroll
    for (int mt = 0; mt < 4; mt++)
        #pragma unroll
        for (int nt = 0; nt < 4; nt++)
            #pragma unroll
            for (int r = 0; r < 4; r++)
                lp[(mt * 16 + (lane >> 4) * 4 + r) * 64 + nt * 16 + frow] = (bf16_t)S[mt][nt][r];
    __syncthreads();
    floatx4 O[4][2] = {};
    #pragma unroll
    for (int ks = 0; ks < 2; ks++) {
        bf16x8 vbs[2];
        #pragma unroll
        for (int nt = 0; nt < 2; nt++)
            #pragma unroll
            for (int j = 0; j < 8; j++)
                vbs[nt][j] = lv[(ks * 32 + fk + j) * 32 + nt * 16 + frow];
        #pragma unroll
        for (int mt = 0; mt < 4; mt++) {
            bf16x8 pa = *(const bf16x8*)&lp[(mt * 16 + frow) * 64 + ks * 32 + fk];
            #pragma unroll
            for (int nt = 0; nt < 2; nt++)
                O[mt][nt] = __builtin_amdgcn_mfma_f32_16x16x32_bf16(pa, vbs[nt], O[mt][nt], 0, 0, 0);
        }
    }
    #pragma unroll
    for (int mt = 0; mt < 4; mt++) {
        #pragma unroll
        for (int r = 0; r < 4; r++) {
            int qr = mt * 16 + (lane >> 4) * 4 + r;
            size_t orow = (size_t)trow(qr) * 128 + h * 32;
            #pragma unroll
            for (int nt = 0; nt < 2; nt++)
                out[orow + nt * 16 + frow] = (bf16_t)O[mt][nt][r];
        }
    }
}

extern "C" void kernel_launch(void* const* d_in, const int* in_sizes, int n_in,
                              void* d_out, int out_size, void* d_ws, size_t ws_size,
                              hipStream_t stream) {
    const float* x       = (const float*)d_in[0];
    const float* a_ln1g  = (const float*)d_in[1];
    const float* a_ln1b  = (const float*)d_in[2];
    const float* a_qkvw  = (const float*)d_in[3];
    const float* a_qkvb  = (const float*)d_in[4];
    const float* a_projw = (const float*)d_in[5];
    const float* a_projb = (const float*)d_in[6];
    const float* a_ln2g  = (const float*)d_in[7];
    const float* a_ln2b  = (const float*)d_in[8];
    const float* a_fc1w  = (const float*)d_in[9];
    const float* a_fc1b  = (const float*)d_in[10];
    const float* a_fc2w  = (const float*)d_in[11];
    const float* a_fc2b  = (const float*)d_in[12];
    const float* b_ln1g  = (const float*)d_in[13];
    const float* b_ln1b  = (const float*)d_in[14];
    const float* b_qkvw  = (const float*)d_in[15];
    const float* b_qkvb  = (const float*)d_in[16];
    const float* b_projw = (const float*)d_in[17];
    const float* b_projb = (const float*)d_in[18];
    const float* b_ln2g  = (const float*)d_in[19];
    const float* b_ln2b  = (const float*)d_in[20];
    const float* b_fc1w  = (const float*)d_in[21];
    const float* b_fc1b  = (const float*)d_in[22];
    const float* b_fc2w  = (const float*)d_in[23];
    const float* b_fc2b  = (const float*)d_in[24];
    const float* mlng    = (const float*)d_in[25];
    const float* mlnb    = (const float*)d_in[26];
    const float* redw    = (const float*)d_in[27];
    float* out = (float*)d_out;

    // workspace layout (~133 MB)
    char* p = (char*)d_ws;
    float*  buf_x   = (float*)p;  p += (size_t)NTOK * 128 * 4;   // fp32 residual stream
    bf16_t* buf_ln  = (bf16_t*)p; p += (size_t)NTOK * 128 * 2;   // LN output (bf16)
    bf16_t* buf_big = (bf16_t*)p; p += (size_t)NTOK * 512 * 2;   // qkv+attn | h | merged
    bf16_t* wt      = (bf16_t*)p;                                // transposed weights
    bf16_t* buf_qkv  = buf_big;                    // NTOK*384
    bf16_t* buf_attn = buf_big + (size_t)NTOK * 384;  // NTOK*128
    bf16_t* aqkvT  = wt;
    bf16_t* aprojT = aqkvT  + 384 * 128;
    bf16_t* afc1T  = aprojT + 128 * 128;
    bf16_t* afc2T  = afc1T  + 512 * 128;
    bf16_t* bqkvT  = afc2T  + 128 * 512;
    bf16_t* bprojT = bqkvT  + 384 * 128;
    bf16_t* bfc1T  = bprojT + 128 * 128;
    bf16_t* bfc2T  = bfc1T  + 512 * 128;
    bf16_t* redT   = bfc2T  + 128 * 512;

    auto T = [&](const float* in, bf16_t* o, int K, int N) {
        kconv_t<<<dim3((K * N + 255) / 256), dim3(256), 0, stream>>>(in, o, K, N);
    };
    T(a_qkvw, aqkvT, 128, 384); T(a_projw, aprojT, 128, 128);
    T(a_fc1w, afc1T, 128, 512); T(a_fc2w, afc2T, 512, 128);
    T(b_qkvw, bqkvT, 128, 384); T(b_projw, bprojT, 128, 128);
    T(b_fc1w, bfc1T, 128, 512); T(b_fc2w, bfc2T, 512, 128);
    T(redw, redT, 512, 256);

    const dim3 blk256(256);
    const int MG = NTOK / 64;  // 1152

    // ---- block A (W-MSA, shift 0)
    kln128<<<dim3(NTOK / 4), blk256, 0, stream>>>(x, a_ln1g, a_ln1b, buf_ln, NTOK);
    gemm64<0><<<dim3(6, MG), blk256, 0, stream>>>(buf_ln, aqkvT, a_qkvb, nullptr, nullptr, buf_qkv, NTOK, 384, 128);
    kattn<<<dim3(1152 * 4), dim3(64), 0, stream>>>(buf_qkv, buf_attn, 0);
    gemm64<1><<<dim3(2, MG), blk256, 0, stream>>>(buf_attn, aprojT, a_projb, x, buf_x, nullptr, NTOK, 128, 128);
    kln128<<<dim3(NTOK / 4), blk256, 0, stream>>>(buf_x, a_ln2g, a_ln2b, buf_ln, NTOK);
    gemm64<2><<<dim3(8, MG), blk256, 0, stream>>>(buf_ln, afc1T, a_fc1b, nullptr, nullptr, buf_big, NTOK, 512, 128);
    gemm64<1><<<dim3(2, MG), blk256, 0, stream>>>(buf_big, afc2T, a_fc2b, buf_x, buf_x, nullptr, NTOK, 128, 512);

    // ---- block B (SW-MSA, shift 4)
    kln128<<<dim3(NTOK / 4), blk256, 0, stream>>>(buf_x, b_ln1g, b_ln1b, buf_ln, NTOK);
    gemm64<0><<<dim3(6, MG), blk256, 0, stream>>>(buf_ln, bqkvT, b_qkvb, nullptr, nullptr, buf_qkv, NTOK, 384, 128);
    kattn<<<dim3(1152 * 4), dim3(64), 0, stream>>>(buf_qkv, buf_attn, 4);
    gemm64<1><<<dim3(2, MG), blk256, 0, stream>>>(buf_attn, bprojT, b_projb, buf_x, buf_x, nullptr, NTOK, 128, 128);
    kln128<<<dim3(NTOK / 4), blk256, 0, stream>>>(buf_x, b_ln2g, b_ln2b, buf_ln, NTOK);
    gemm64<2><<<dim3(8, MG), blk256, 0, stream>>>(buf_ln, bfc1T, b_fc1b, nullptr, nullptr, buf_big, NTOK, 512, 128);
    gemm64<1><<<dim3(2, MG), blk256, 0, stream>>>(buf_big, bfc2T, b_fc2b, buf_x, buf_x, nullptr, NTOK, 128, 512);

    // ---- patch merge
    kmergeln<<<dim3(18432 / 4), blk256, 0, stream>>>(buf_x, mlng, mlnb, buf_big);
    gemm64<3><<<dim3(4, 288), blk256, 0, stream>>>(buf_big, redT, nullptr, nullptr, out, nullptr, 18432, 256, 512);
}

// Round 2
// 496.566 us; speedup vs baseline: 1.0570x; 1.0570x over previous
//
#include <hip/hip_runtime.h>
#include <hip/hip_bf16.h>

typedef __bf16 bf16_t;
typedef __bf16 bf16x2 __attribute__((ext_vector_type(2)));
typedef __bf16 bf16x8 __attribute__((ext_vector_type(8)));
typedef float floatx4 __attribute__((ext_vector_type(4)));

#define NTOK 73728   // 8*96*96

// async global->LDS, 16B per lane. LDS dest must be wave-uniform base + lane*16.
__device__ __forceinline__ void gl16(const bf16_t* g, bf16_t* l) {
    __builtin_amdgcn_global_load_lds((const __attribute__((address_space(1))) void*)g,
                                     (__attribute__((address_space(3))) void*)l, 16, 0, 0);
}

// ---------------- all 9 weight transposes in one dispatch: dst[n*K+k] = src[k*N+n]
struct TPack {
    const float* src[9];
    bf16_t* dst[9];
    int K[9], N[9];
};
__global__ __launch_bounds__(256) void kconv_t9(TPack p) {
    int seg = blockIdx.y;
    int K = p.K[seg], N = p.N[seg];
    int idx = blockIdx.x * 256 + threadIdx.x;
    if (idx >= K * N) return;
    int n = idx / K, k = idx - n * K;
    p.dst[seg][idx] = (bf16_t)p.src[seg][k * N + n];
}

// ---------------- LayerNorm over 128 channels, fp32 in -> bf16 out (wave per row)
__global__ __launch_bounds__(256) void kln128(const float* __restrict__ x, const float* __restrict__ g,
                                              const float* __restrict__ bta, bf16_t* __restrict__ out, int M) {
    int row = blockIdx.x * 4 + (threadIdx.x >> 6);
    int lane = threadIdx.x & 63;
    if (row >= M) return;
    float2 v = *(const float2*)&x[row * 128 + lane * 2];
    float s = v.x + v.y;
    float sq = v.x * v.x + v.y * v.y;
    #pragma unroll
    for (int d = 1; d < 64; d <<= 1) { s += __shfl_xor(s, d, 64); sq += __shfl_xor(sq, d, 64); }
    float m = s * (1.0f / 128.0f);
    float var = sq * (1.0f / 128.0f) - m * m;
    float inv = 1.0f / sqrtf(var + 1e-5f);
    float2 gg = *(const float2*)&g[lane * 2];
    float2 bb = *(const float2*)&bta[lane * 2];
    bf16x2 o;
    o[0] = (bf16_t)((v.x - m) * inv * gg.x + bb.x);
    o[1] = (bf16_t)((v.y - m) * inv * gg.y + bb.y);
    *(bf16x2*)&out[row * 128 + lane * 2] = o;
}

// ---------------- patch-merge gather + LayerNorm over 512 -> bf16 (wave per output row)
__global__ __launch_bounds__(256) void kmergeln(const float* __restrict__ x, const float* __restrict__ g,
                                                const float* __restrict__ bta, bf16_t* __restrict__ out) {
    int row = blockIdx.x * 4 + (threadIdx.x >> 6);   // 0..18431
    int lane = threadIdx.x & 63;
    int b = row / 2304; int rr = row - b * 2304;
    int i2 = rr / 48, j2 = rr - i2 * 48;
    int q = lane >> 4;               // concat quadrant: 0:(0,0) 1:(1,0) 2:(0,1) 3:(1,1)
    int cc = (lane & 15) * 8;        // channel within 128
    int di = q & 1, dj = q >> 1;
    int src = ((b * 96 + i2 * 2 + di) * 96 + (j2 * 2 + dj)) * 128 + cc;
    float4 a0 = *(const float4*)&x[src];
    float4 a1 = *(const float4*)&x[src + 4];
    float s  = a0.x + a0.y + a0.z + a0.w + a1.x + a1.y + a1.z + a1.w;
    float sq = a0.x*a0.x + a0.y*a0.y + a0.z*a0.z + a0.w*a0.w
             + a1.x*a1.x + a1.y*a1.y + a1.z*a1.z + a1.w*a1.w;
    #pragma unroll
    for (int d = 1; d < 64; d <<= 1) { s += __shfl_xor(s, d, 64); sq += __shfl_xor(sq, d, 64); }
    float m = s * (1.0f / 512.0f);
    float var = sq * (1.0f / 512.0f) - m * m;
    float inv = 1.0f / sqrtf(var + 1e-5f);
    int c = q * 128 + cc;
    float4 g0 = *(const float4*)&g[c];
    float4 g1 = *(const float4*)&g[c + 4];
    float4 b0 = *(const float4*)&bta[c];
    float4 b1 = *(const float4*)&bta[c + 4];
    bf16x8 o;
    o[0] = (bf16_t)((a0.x - m) * inv * g0.x + b0.x);
    o[1] = (bf16_t)((a0.y - m) * inv * g0.y + b0.y);
    o[2] = (bf16_t)((a0.z - m) * inv * g0.z + b0.z);
    o[3] = (bf16_t)((a0.w - m) * inv * g0.w + b0.w);
    o[4] = (bf16_t)((a1.x - m) * inv * g1.x + b1.x);
    o[5] = (bf16_t)((a1.y - m) * inv * g1.y + b1.y);
    o[6] = (bf16_t)((a1.z - m) * inv * g1.z + b1.z);
    o[7] = (bf16_t)((a1.w - m) * inv * g1.w + b1.w);
    *(bf16x8*)&out[row * 512 + c] = o;
}

// ---------------- GEMM: out(M,N) = A(M,K) @ Bt(N,K)^T (+bias)(+res)(gelu)
// 128x128 tile, BK=32, 4 waves each computing a 64x64 quadrant (4x4 MFMA 16x16x32).
// Staging via global_load_lds width=16 (m97 pattern). M%128==0, N%128==0, K%32==0.
// MODE 0: bf16 out = acc+bias   (qkv)
// MODE 1: f32 out = res + acc + bias  (proj / fc2, residual)
// MODE 2: bf16 out = gelu(acc+bias)   (fc1)
// MODE 3: f32 out = acc               (patch-merge reduction)
template<int MODE>
__global__ __launch_bounds__(256) void gemm128(const bf16_t* __restrict__ A,
                                               const bf16_t* __restrict__ Bt,
                                               const float* __restrict__ bias,
                                               const float* __restrict__ res,
                                               float* __restrict__ outf,
                                               bf16_t* __restrict__ outh,
                                               int M, int N, int K) {
    alignas(16) __shared__ bf16_t lA[128 * 32];
    alignas(16) __shared__ bf16_t lB[128 * 32];
    const int tid = threadIdx.x;
    const int lane = tid & 63;
    const int wv = tid >> 6;                     // 2x2 waves -> 64x64 quadrants
    const int wm = (wv & 1) * 64, wn = (wv >> 1) * 64;
    const int frow = lane & 15, fq = lane >> 4;  // fragment row / k-quad
    const int rowA = blockIdx.y * 128;
    const int rowB = blockIdx.x * 128;
    // staging: thread t stages chunk t (rows 0-63) and chunk 256+t (rows 64-127)
    const int srow = tid >> 2, scol = (tid & 3) * 8;
    const bf16_t* pa = A + (size_t)(rowA + srow) * K + scol;
    const bf16_t* pb = Bt + (size_t)(rowB + srow) * K + scol;
    const size_t half = (size_t)64 * K;
    floatx4 acc[4][4] = {};
    for (int k0 = 0; k0 < K; k0 += 32) {
        __syncthreads();
        gl16(pa + k0,        &lA[tid * 8]);
        gl16(pa + half + k0, &lA[2048 + tid * 8]);
        gl16(pb + k0,        &lB[tid * 8]);
        gl16(pb + half + k0, &lB[2048 + tid * 8]);
        __syncthreads();
        bf16x8 af[4], bfr[4];
        #pragma unroll
        for (int i = 0; i < 4; i++) {
            af[i]  = *(const bf16x8*)&lA[(wm + i * 16 + frow) * 32 + fq * 8];
            bfr[i] = *(const bf16x8*)&lB[(wn + i * 16 + frow) * 32 + fq * 8];
        }
        #pragma unroll
        for (int i = 0; i < 4; i++)
            #pragma unroll
            for (int j = 0; j < 4; j++)
                acc[i][j] = __builtin_amdgcn_mfma_f32_16x16x32_bf16(af[i], bfr[j], acc[i][j], 0, 0, 0);
    }
    #pragma unroll
    for (int i = 0; i < 4; i++) {
        #pragma unroll
        for (int j = 0; j < 4; j++) {
            int col = rowB + wn + j * 16 + frow;
            float bs = (MODE == 3) ? 0.0f : bias[col];
            #pragma unroll
            for (int r = 0; r < 4; r++) {
                int row = rowA + wm + i * 16 + fq * 4 + r;
                float v = acc[i][j][r] + bs;
                size_t off = (size_t)row * N + col;
                if (MODE == 0) {
                    outh[off] = (bf16_t)v;
                } else if (MODE == 1) {
                    outf[off] = res[off] + v;
                } else if (MODE == 2) {
                    outh[off] = (bf16_t)(0.5f * v * (1.0f + erff(v * 0.70710678118654752f)));
                } else {
                    outf[off] = v;
                }
            }
        }
    }
}

// ---------------- fused window attention: one wave per (window, head)
__global__ __launch_bounds__(64) void kattn(const bf16_t* __restrict__ qkv, bf16_t* __restrict__ out, int shift) {
    alignas(16) __shared__ bf16_t lp[64 * 64];  // P matrix, [query][key]
    alignas(16) __shared__ bf16_t lv[64 * 32];  // V, [key][feat]
    int blk = blockIdx.x;
    int win = blk >> 2, h = blk & 3;
    int b = win / 144; int wr = win - b * 144;
    int wi = wr / 12, wj = wr - wi * 12;
    int ri0 = wi * 8, rj0 = wj * 8;
    int lane = threadIdx.x;
    auto trow = [&](int n) {
        int oi = ri0 + (n >> 3) + shift; oi = (oi >= 96) ? oi - 96 : oi;
        int oj = rj0 + (n & 7) + shift;  oj = (oj >= 96) ? oj - 96 : oj;
        return (b * 96 + oi) * 96 + oj;
    };
    {
        size_t base = (size_t)trow(lane) * 384 + 256 + h * 32;
        *(uint4*)&lv[lane * 32]      = *(const uint4*)&qkv[base];
        *(uint4*)&lv[lane * 32 + 8]  = *(const uint4*)&qkv[base + 8];
        *(uint4*)&lv[lane * 32 + 16] = *(const uint4*)&qkv[base + 16];
        *(uint4*)&lv[lane * 32 + 24] = *(const uint4*)&qkv[base + 24];
    }
    int frow = lane & 15, fk = (lane >> 4) * 8;
    bf16x8 qf[4], kf[4];
    #pragma unroll
    for (int t = 0; t < 4; t++) {
        size_t rq = (size_t)trow(t * 16 + frow) * 384;
        qf[t] = *(const bf16x8*)&qkv[rq + h * 32 + fk];
        kf[t] = *(const bf16x8*)&qkv[rq + 128 + h * 32 + fk];
    }
    floatx4 S[4][4] = {};
    #pragma unroll
    for (int mt = 0; mt < 4; mt++)
        #pragma unroll
        for (int nt = 0; nt < 4; nt++)
            S[mt][nt] = __builtin_amdgcn_mfma_f32_16x16x32_bf16(qf[mt], kf[nt], S[mt][nt], 0, 0, 0);
    const float scale = 0.17677669529663687f;  // 32^-0.5
    #pragma unroll
    for (int mt = 0; mt < 4; mt++)
        #pragma unroll
        for (int nt = 0; nt < 4; nt++)
            #pragma unroll
            for (int r = 0; r < 4; r++) S[mt][nt][r] *= scale;
    if (shift > 0) {
        auto grpn = [&](int n) {
            int ri = ri0 + (n >> 3), rj = rj0 + (n & 7);
            int gr = (ri < 88) ? 0 : ((ri < 92) ? 1 : 2);
            int gc = (rj < 88) ? 0 : ((rj < 92) ? 1 : 2);
            return gr * 3 + gc;
        };
        int gk[4];
        #pragma unroll
        for (int nt = 0; nt < 4; nt++) gk[nt] = grpn(nt * 16 + frow);
        #pragma unroll
        for (int mt = 0; mt < 4; mt++)
            #pragma unroll
            for (int r = 0; r < 4; r++) {
                int gq = grpn(mt * 16 + (lane >> 4) * 4 + r);
                #pragma unroll
                for (int nt = 0; nt < 4; nt++)
                    if (gq != gk[nt]) S[mt][nt][r] = -1e30f;
            }
    }
    #pragma unroll
    for (int mt = 0; mt < 4; mt++) {
        #pragma unroll
        for (int r = 0; r < 4; r++) {
            float mx = fmaxf(fmaxf(S[mt][0][r], S[mt][1][r]), fmaxf(S[mt][2][r], S[mt][3][r]));
            #pragma unroll
            for (int d = 1; d < 16; d <<= 1) mx = fmaxf(mx, __shfl_xor(mx, d, 64));
            float sm = 0.0f;
            #pragma unroll
            for (int nt = 0; nt < 4; nt++) {
                float p = __expf(S[mt][nt][r] - mx);
                S[mt][nt][r] = p;
                sm += p;
            }
            #pragma unroll
            for (int d = 1; d < 16; d <<= 1) sm += __shfl_xor(sm, d, 64);
            float inv = 1.0f / sm;
            #pragma unroll
            for (int nt = 0; nt < 4; nt++) S[mt][nt][r] *= inv;
        }
    }
    #pragma unroll
    for (int mt = 0; mt < 4; mt++)
        #pragma unroll
        for (int nt = 0; nt < 4; nt++)
            #pragma unroll
            for (int r = 0; r < 4; r++)
                lp[(mt * 16 + (lane >> 4) * 4 + r) * 64 + nt * 16 + frow] = (bf16_t)S[mt][nt][r];
    __syncthreads();
    floatx4 O[4][2] = {};
    #pragma unroll
    for (int ks = 0; ks < 2; ks++) {
        bf16x8 vbs[2];
        #pragma unroll
        for (int nt = 0; nt < 2; nt++)
            #pragma unroll
            for (int j = 0; j < 8; j++)
                vbs[nt][j] = lv[(ks * 32 + fk + j) * 32 + nt * 16 + frow];
        #pragma unroll
        for (int mt = 0; mt < 4; mt++) {
            bf16x8 pa = *(const bf16x8*)&lp[(mt * 16 + frow) * 64 + ks * 32 + fk];
            #pragma unroll
            for (int nt = 0; nt < 2; nt++)
                O[mt][nt] = __builtin_amdgcn_mfma_f32_16x16x32_bf16(pa, vbs[nt], O[mt][nt], 0, 0, 0);
        }
    }
    #pragma unroll
    for (int mt = 0; mt < 4; mt++) {
        #pragma unroll
        for (int r = 0; r < 4; r++) {
            int qr = mt * 16 + (lane >> 4) * 4 + r;
            size_t orow = (size_t)trow(qr) * 128 + h * 32;
            #pragma unroll
            for (int nt = 0; nt < 2; nt++)
                out[orow + nt * 16 + frow] = (bf16_t)O[mt][nt][r];
        }
    }
}

extern "C" void kernel_launch(void* const* d_in, const int* in_sizes, int n_in,
                              void* d_out, int out_size, void* d_ws, size_t ws_size,
                              hipStream_t stream) {
    const float* x       = (const float*)d_in[0];
    const float* a_ln1g  = (const float*)d_in[1];
    const float* a_ln1b  = (const float*)d_in[2];
    const float* a_qkvw  = (const float*)d_in[3];
    const float* a_qkvb  = (const float*)d_in[4];
    const float* a_projw = (const float*)d_in[5];
    const float* a_projb = (const float*)d_in[6];
    const float* a_ln2g  = (const float*)d_in[7];
    const float* a_ln2b  = (const float*)d_in[8];
    const float* a_fc1w  = (const float*)d_in[9];
    const float* a_fc1b  = (const float*)d_in[10];
    const float* a_fc2w  = (const float*)d_in[11];
    const float* a_fc2b  = (const float*)d_in[12];
    const float* b_ln1g  = (const float*)d_in[13];
    const float* b_ln1b  = (const float*)d_in[14];
    const float* b_qkvw  = (const float*)d_in[15];
    const float* b_qkvb  = (const float*)d_in[16];
    const float* b_projw = (const float*)d_in[17];
    const float* b_projb = (const float*)d_in[18];
    const float* b_ln2g  = (const float*)d_in[19];
    const float* b_ln2b  = (const float*)d_in[20];
    const float* b_fc1w  = (const float*)d_in[21];
    const float* b_fc1b  = (const float*)d_in[22];
    const float* b_fc2w  = (const float*)d_in[23];
    const float* b_fc2b  = (const float*)d_in[24];
    const float* mlng    = (const float*)d_in[25];
    const float* mlnb    = (const float*)d_in[26];
    const float* redw    = (const float*)d_in[27];
    float* out = (float*)d_out;

    // workspace layout
    char* p = (char*)d_ws;
    float*  buf_x   = (float*)p;  p += (size_t)NTOK * 128 * 4;   // fp32 residual stream
    bf16_t* buf_ln  = (bf16_t*)p; p += (size_t)NTOK * 128 * 2;   // LN output (bf16)
    bf16_t* buf_big = (bf16_t*)p; p += (size_t)NTOK * 512 * 2;   // qkv+attn | h | merged
    bf16_t* wt      = (bf16_t*)p;                                // transposed weights
    bf16_t* buf_qkv  = buf_big;                       // NTOK*384
    bf16_t* buf_attn = buf_big + (size_t)NTOK * 384;  // NTOK*128
    bf16_t* aqkvT  = wt;
    bf16_t* aprojT = aqkvT  + 384 * 128;
    bf16_t* afc1T  = aprojT + 128 * 128;
    bf16_t* afc2T  = afc1T  + 512 * 128;
    bf16_t* bqkvT  = afc2T  + 128 * 512;
    bf16_t* bprojT = bqkvT  + 384 * 128;
    bf16_t* bfc1T  = bprojT + 128 * 128;
    bf16_t* bfc2T  = bfc1T  + 512 * 128;
    bf16_t* redT   = bfc2T  + 128 * 512;

    // all weight transposes, one dispatch
    TPack tp;
    const float* srcs[9] = {a_qkvw, a_projw, a_fc1w, a_fc2w, b_qkvw, b_projw, b_fc1w, b_fc2w, redw};
    bf16_t* dsts[9] = {aqkvT, aprojT, afc1T, afc2T, bqkvT, bprojT, bfc1T, bfc2T, redT};
    int Ks[9] = {128, 128, 128, 512, 128, 128, 128, 512, 512};
    int Ns[9] = {384, 128, 512, 128, 384, 128, 512, 128, 256};
    for (int i = 0; i < 9; i++) { tp.src[i] = srcs[i]; tp.dst[i] = dsts[i]; tp.K[i] = Ks[i]; tp.N[i] = Ns[i]; }
    kconv_t9<<<dim3(512, 9), dim3(256), 0, stream>>>(tp);

    const dim3 blk256(256);
    const int MG = NTOK / 128;  // 576

    // ---- block A (W-MSA, shift 0)
    kln128<<<dim3(NTOK / 4), blk256, 0, stream>>>(x, a_ln1g, a_ln1b, buf_ln, NTOK);
    gemm128<0><<<dim3(3, MG), blk256, 0, stream>>>(buf_ln, aqkvT, a_qkvb, nullptr, nullptr, buf_qkv, NTOK, 384, 128);
    kattn<<<dim3(1152 * 4), dim3(64), 0, stream>>>(buf_qkv, buf_attn, 0);
    gemm128<1><<<dim3(1, MG), blk256, 0, stream>>>(buf_attn, aprojT, a_projb, x, buf_x, nullptr, NTOK, 128, 128);
    kln128<<<dim3(NTOK / 4), blk256, 0, stream>>>(buf_x, a_ln2g, a_ln2b, buf_ln, NTOK);
    gemm128<2><<<dim3(4, MG), blk256, 0, stream>>>(buf_ln, afc1T, a_fc1b, nullptr, nullptr, buf_big, NTOK, 512, 128);
    gemm128<1><<<dim3(1, MG), blk256, 0, stream>>>(buf_big, afc2T, a_fc2b, buf_x, buf_x, nullptr, NTOK, 128, 512);

    // ---- block B (SW-MSA, shift 4)
    kln128<<<dim3(NTOK / 4), blk256, 0, stream>>>(buf_x, b_ln1g, b_ln1b, buf_ln, NTOK);
    gemm128<0><<<dim3(3, MG), blk256, 0, stream>>>(buf_ln, bqkvT, b_qkvb, nullptr, nullptr, buf_qkv, NTOK, 384, 128);
    kattn<<<dim3(1152 * 4), dim3(64), 0, stream>>>(buf_qkv, buf_attn, 4);
    gemm128<1><<<dim3(1, MG), blk256, 0, stream>>>(buf_attn, bprojT, b_projb, buf_x, buf_x, nullptr, NTOK, 128, 128);
    kln128<<<dim3(NTOK / 4), blk256, 0, stream>>>(buf_x, b_ln2g, b_ln2b, buf_ln, NTOK);
    gemm128<2><<<dim3(4, MG), blk256, 0, stream>>>(buf_ln, bfc1T, b_fc1b, nullptr, nullptr, buf_big, NTOK, 512, 128);
    gemm128<1><<<dim3(1, MG), blk256, 0, stream>>>(buf_big, bfc2T, b_fc2b, buf_x, buf_x, nullptr, NTOK, 128, 512);

    // ---- patch merge
    kmergeln<<<dim3(18432 / 4), blk256, 0, stream>>>(buf_x, mlng, mlnb, buf_big);
    gemm128<3><<<dim3(2, 144), blk256, 0, stream>>>(buf_big, redT, nullptr, nullptr, out, nullptr, 18432, 256, 512);
}

// Round 3
// 460.615 us; speedup vs baseline: 1.1395x; 1.0780x over previous
//
#include <hip/hip_runtime.h>
#include <hip/hip_bf16.h>

typedef __bf16 bf16_t;
typedef __bf16 bf16x2 __attribute__((ext_vector_type(2)));
typedef __bf16 bf16x8 __attribute__((ext_vector_type(8)));
typedef float floatx4 __attribute__((ext_vector_type(4)));

#define NTOK 73728   // 8*96*96

// async global->LDS, 16B per lane. LDS dest must be wave-uniform base + lane*16.
__device__ __forceinline__ void gl16(const bf16_t* g, bf16_t* l) {
    __builtin_amdgcn_global_load_lds((const __attribute__((address_space(1))) void*)g,
                                     (__attribute__((address_space(3))) void*)l, 16, 0, 0);
}

// ---------------- all 9 weight transposes in one dispatch: dst[n*K+k] = src[k*N+n]
struct TPack {
    const float* src[9];
    bf16_t* dst[9];
    int K[9], N[9];
};
__global__ __launch_bounds__(256) void kconv_t9(TPack p) {
    int seg = blockIdx.y;
    int K = p.K[seg], N = p.N[seg];
    int idx = blockIdx.x * 256 + threadIdx.x;
    if (idx >= K * N) return;
    int n = idx / K, k = idx - n * K;
    p.dst[seg][idx] = (bf16_t)p.src[seg][k * N + n];
}

// ---------------- LayerNorm over 128 channels, fp32 in -> bf16 out (wave per row)
__global__ __launch_bounds__(256) void kln128(const float* __restrict__ x, const float* __restrict__ g,
                                              const float* __restrict__ bta, bf16_t* __restrict__ out, int M) {
    int row = blockIdx.x * 4 + (threadIdx.x >> 6);
    int lane = threadIdx.x & 63;
    if (row >= M) return;
    float2 v = *(const float2*)&x[row * 128 + lane * 2];
    float s = v.x + v.y;
    float sq = v.x * v.x + v.y * v.y;
    #pragma unroll
    for (int d = 1; d < 64; d <<= 1) { s += __shfl_xor(s, d, 64); sq += __shfl_xor(sq, d, 64); }
    float m = s * (1.0f / 128.0f);
    float var = sq * (1.0f / 128.0f) - m * m;
    float inv = 1.0f / sqrtf(var + 1e-5f);
    float2 gg = *(const float2*)&g[lane * 2];
    float2 bb = *(const float2*)&bta[lane * 2];
    bf16x2 o;
    o[0] = (bf16_t)((v.x - m) * inv * gg.x + bb.x);
    o[1] = (bf16_t)((v.y - m) * inv * gg.y + bb.y);
    *(bf16x2*)&out[row * 128 + lane * 2] = o;
}

// ---------------- patch-merge gather + LayerNorm over 512 -> bf16 (wave per output row)
__global__ __launch_bounds__(256) void kmergeln(const float* __restrict__ x, const float* __restrict__ g,
                                                const float* __restrict__ bta, bf16_t* __restrict__ out) {
    int row = blockIdx.x * 4 + (threadIdx.x >> 6);   // 0..18431
    int lane = threadIdx.x & 63;
    int b = row / 2304; int rr = row - b * 2304;
    int i2 = rr / 48, j2 = rr - i2 * 48;
    int q = lane >> 4;               // concat quadrant: 0:(0,0) 1:(1,0) 2:(0,1) 3:(1,1)
    int cc = (lane & 15) * 8;        // channel within 128
    int di = q & 1, dj = q >> 1;
    int src = ((b * 96 + i2 * 2 + di) * 96 + (j2 * 2 + dj)) * 128 + cc;
    float4 a0 = *(const float4*)&x[src];
    float4 a1 = *(const float4*)&x[src + 4];
    float s  = a0.x + a0.y + a0.z + a0.w + a1.x + a1.y + a1.z + a1.w;
    float sq = a0.x*a0.x + a0.y*a0.y + a0.z*a0.z + a0.w*a0.w
             + a1.x*a1.x + a1.y*a1.y + a1.z*a1.z + a1.w*a1.w;
    #pragma unroll
    for (int d = 1; d < 64; d <<= 1) { s += __shfl_xor(s, d, 64); sq += __shfl_xor(sq, d, 64); }
    float m = s * (1.0f / 512.0f);
    float var = sq * (1.0f / 512.0f) - m * m;
    float inv = 1.0f / sqrtf(var + 1e-5f);
    int c = q * 128 + cc;
    float4 g0 = *(const float4*)&g[c];
    float4 g1 = *(const float4*)&g[c + 4];
    float4 b0 = *(const float4*)&bta[c];
    float4 b1 = *(const float4*)&bta[c + 4];
    bf16x8 o;
    o[0] = (bf16_t)((a0.x - m) * inv * g0.x + b0.x);
    o[1] = (bf16_t)((a0.y - m) * inv * g0.y + b0.y);
    o[2] = (bf16_t)((a0.z - m) * inv * g0.z + b0.z);
    o[3] = (bf16_t)((a0.w - m) * inv * g0.w + b0.w);
    o[4] = (bf16_t)((a1.x - m) * inv * g1.x + b1.x);
    o[5] = (bf16_t)((a1.y - m) * inv * g1.y + b1.y);
    o[6] = (bf16_t)((a1.z - m) * inv * g1.z + b1.z);
    o[7] = (bf16_t)((a1.w - m) * inv * g1.w + b1.w);
    *(bf16x8*)&out[row * 512 + c] = o;
}

// ---------------- GEMM: out(M,N) = A(M,K) @ Bt(N,K)^T (+bias)(+res)(gelu)
// 64x128 tile (memory-bound shape: small tile -> high occupancy, deep load pipeline).
// BK=64 staged as two k-panels of 32 (keeps 64B LDS row stride = m97's benign bank
// pattern AND the global_load_lds linear-dest constraint). 4 waves, each 32x64 (2x4 MFMA).
// MODE 0: bf16 out = acc+bias   (qkv)
// MODE 1: f32 out = res + acc + bias  (proj / fc2, residual)
// MODE 2: bf16 out = gelu(acc+bias)   (fc1) -- sigmoid-form tanh gelu, no erff
// MODE 3: f32 out = acc               (patch-merge reduction)
template<int MODE>
__global__ __launch_bounds__(256, 5) void gemm64x128(const bf16_t* __restrict__ A,
                                                     const bf16_t* __restrict__ Bt,
                                                     const float* __restrict__ bias,
                                                     const float* __restrict__ res,
                                                     float* __restrict__ outf,
                                                     bf16_t* __restrict__ outh,
                                                     int M, int N, int K) {
    alignas(16) __shared__ bf16_t lA[2 * 64 * 32];    // [s][row][32]  8KB
    alignas(16) __shared__ bf16_t lB[2 * 128 * 32];   // [s][row][32] 16KB
    const int tid = threadIdx.x;
    const int lane = tid & 63;
    const int wv = tid >> 6;
    const int wm = (wv & 1) * 32;       // wave row offset (2 groups)
    const int wn = (wv >> 1) * 64;      // wave col offset (2 groups)
    const int frow = lane & 15, fq = lane >> 4;
    const int rowA = blockIdx.y * 64;
    const int rowB = blockIdx.x * 128;
    const int sr = tid >> 2, sc = (tid & 3) * 8;   // staging: 4 threads/row, 8 elems each
    const bf16_t* pa = A + (size_t)(rowA + sr) * K + sc;
    const bf16_t* pb0 = Bt + (size_t)(rowB + sr) * K + sc;
    const bf16_t* pb1 = Bt + (size_t)(rowB + 64 + sr) * K + sc;
    floatx4 acc[2][4] = {};
    for (int k0 = 0; k0 < K; k0 += 64) {
        __syncthreads();
        gl16(pa  + k0,      &lA[tid * 8]);            // s=0, rows 0..63
        gl16(pa  + k0 + 32, &lA[2048 + tid * 8]);     // s=1
        gl16(pb0 + k0,      &lB[tid * 8]);            // s=0, rows 0..63
        gl16(pb1 + k0,      &lB[2048 + tid * 8]);     // s=0, rows 64..127
        gl16(pb0 + k0 + 32, &lB[4096 + tid * 8]);     // s=1, rows 0..63
        gl16(pb1 + k0 + 32, &lB[4096 + 2048 + tid * 8]);
        __syncthreads();
        #pragma unroll
        for (int s = 0; s < 2; s++) {
            bf16x8 af[2], bfr[4];
            #pragma unroll
            for (int i = 0; i < 2; i++)
                af[i] = *(const bf16x8*)&lA[s * 2048 + (wm + i * 16 + frow) * 32 + fq * 8];
            #pragma unroll
            for (int j = 0; j < 4; j++)
                bfr[j] = *(const bf16x8*)&lB[s * 4096 + (wn + j * 16 + frow) * 32 + fq * 8];
            #pragma unroll
            for (int i = 0; i < 2; i++)
                #pragma unroll
                for (int j = 0; j < 4; j++)
                    acc[i][j] = __builtin_amdgcn_mfma_f32_16x16x32_bf16(af[i], bfr[j], acc[i][j], 0, 0, 0);
        }
    }
    #pragma unroll
    for (int i = 0; i < 2; i++) {
        #pragma unroll
        for (int j = 0; j < 4; j++) {
            int col = rowB + wn + j * 16 + frow;
            float bs = (MODE == 3) ? 0.0f : bias[col];
            #pragma unroll
            for (int r = 0; r < 4; r++) {
                int row = rowA + wm + i * 16 + fq * 4 + r;
                float v = acc[i][j][r] + bs;
                size_t off = (size_t)row * N + col;
                if (MODE == 0) {
                    outh[off] = (bf16_t)v;
                } else if (MODE == 1) {
                    outf[off] = res[off] + v;
                } else if (MODE == 2) {
                    // gelu(v) ~= v * sigmoid(2*0.7978845608*(v + 0.044715 v^3))
                    float u = 1.5957691216057308f * (v + 0.044715f * v * v * v);
                    outh[off] = (bf16_t)(v / (1.0f + __expf(-u)));
                } else {
                    outf[off] = v;
                }
            }
        }
    }
}

// ---------------- fused window attention: one wave per (window, head)
__global__ __launch_bounds__(64) void kattn(const bf16_t* __restrict__ qkv, bf16_t* __restrict__ out, int shift) {
    alignas(16) __shared__ bf16_t lp[64 * 64];  // P matrix, [query][key]
    alignas(16) __shared__ bf16_t lv[64 * 32];  // V, [key][feat]
    int blk = blockIdx.x;
    int win = blk >> 2, h = blk & 3;
    int b = win / 144; int wr = win - b * 144;
    int wi = wr / 12, wj = wr - wi * 12;
    int ri0 = wi * 8, rj0 = wj * 8;
    int lane = threadIdx.x;
    auto trow = [&](int n) {
        int oi = ri0 + (n >> 3) + shift; oi = (oi >= 96) ? oi - 96 : oi;
        int oj = rj0 + (n & 7) + shift;  oj = (oj >= 96) ? oj - 96 : oj;
        return (b * 96 + oi) * 96 + oj;
    };
    {
        size_t base = (size_t)trow(lane) * 384 + 256 + h * 32;
        *(uint4*)&lv[lane * 32]      = *(const uint4*)&qkv[base];
        *(uint4*)&lv[lane * 32 + 8]  = *(const uint4*)&qkv[base + 8];
        *(uint4*)&lv[lane * 32 + 16] = *(const uint4*)&qkv[base + 16];
        *(uint4*)&lv[lane * 32 + 24] = *(const uint4*)&qkv[base + 24];
    }
    int frow = lane & 15, fk = (lane >> 4) * 8;
    bf16x8 qf[4], kf[4];
    #pragma unroll
    for (int t = 0; t < 4; t++) {
        size_t rq = (size_t)trow(t * 16 + frow) * 384;
        qf[t] = *(const bf16x8*)&qkv[rq + h * 32 + fk];
        kf[t] = *(const bf16x8*)&qkv[rq + 128 + h * 32 + fk];
    }
    floatx4 S[4][4] = {};
    #pragma unroll
    for (int mt = 0; mt < 4; mt++)
        #pragma unroll
        for (int nt = 0; nt < 4; nt++)
            S[mt][nt] = __builtin_amdgcn_mfma_f32_16x16x32_bf16(qf[mt], kf[nt], S[mt][nt], 0, 0, 0);
    const float scale = 0.17677669529663687f;  // 32^-0.5
    #pragma unroll
    for (int mt = 0; mt < 4; mt++)
        #pragma unroll
        for (int nt = 0; nt < 4; nt++)
            #pragma unroll
            for (int r = 0; r < 4; r++) S[mt][nt][r] *= scale;
    if (shift > 0) {
        auto grpn = [&](int n) {
            int ri = ri0 + (n >> 3), rj = rj0 + (n & 7);
            int gr = (ri < 88) ? 0 : ((ri < 92) ? 1 : 2);
            int gc = (rj < 88) ? 0 : ((rj < 92) ? 1 : 2);
            return gr * 3 + gc;
        };
        int gk[4];
        #pragma unroll
        for (int nt = 0; nt < 4; nt++) gk[nt] = grpn(nt * 16 + frow);
        #pragma unroll
        for (int mt = 0; mt < 4; mt++)
            #pragma unroll
            for (int r = 0; r < 4; r++) {
                int gq = grpn(mt * 16 + (lane >> 4) * 4 + r);
                #pragma unroll
                for (int nt = 0; nt < 4; nt++)
                    if (gq != gk[nt]) S[mt][nt][r] = -1e30f;
            }
    }
    #pragma unroll
    for (int mt = 0; mt < 4; mt++) {
        #pragma unroll
        for (int r = 0; r < 4; r++) {
            float mx = fmaxf(fmaxf(S[mt][0][r], S[mt][1][r]), fmaxf(S[mt][2][r], S[mt][3][r]));
            #pragma unroll
            for (int d = 1; d < 16; d <<= 1) mx = fmaxf(mx, __shfl_xor(mx, d, 64));
            float sm = 0.0f;
            #pragma unroll
            for (int nt = 0; nt < 4; nt++) {
                float p = __expf(S[mt][nt][r] - mx);
                S[mt][nt][r] = p;
                sm += p;
            }
            #pragma unroll
            for (int d = 1; d < 16; d <<= 1) sm += __shfl_xor(sm, d, 64);
            float inv = 1.0f / sm;
            #pragma unroll
            for (int nt = 0; nt < 4; nt++) S[mt][nt][r] *= inv;
        }
    }
    #pragma unroll
    for (int mt = 0; mt < 4; mt++)
        #pragma unroll
        for (int nt = 0; nt < 4; nt++)
            #pragma unroll
            for (int r = 0; r < 4; r++)
                lp[(mt * 16 + (lane >> 4) * 4 + r) * 64 + nt * 16 + frow] = (bf16_t)S[mt][nt][r];
    __syncthreads();
    floatx4 O[4][2] = {};
    #pragma unroll
    for (int ks = 0; ks < 2; ks++) {
        bf16x8 vbs[2];
        #pragma unroll
        for (int nt = 0; nt < 2; nt++)
            #pragma unroll
            for (int j = 0; j < 8; j++)
                vbs[nt][j] = lv[(ks * 32 + fk + j) * 32 + nt * 16 + frow];
        #pragma unroll
        for (int mt = 0; mt < 4; mt++) {
            bf16x8 pa = *(const bf16x8*)&lp[(mt * 16 + frow) * 64 + ks * 32 + fk];
            #pragma unroll
            for (int nt = 0; nt < 2; nt++)
                O[mt][nt] = __builtin_amdgcn_mfma_f32_16x16x32_bf16(pa, vbs[nt], O[mt][nt], 0, 0, 0);
        }
    }
    #pragma unroll
    for (int mt = 0; mt < 4; mt++) {
        #pragma unroll
        for (int r = 0; r < 4; r++) {
            int qr = mt * 16 + (lane >> 4) * 4 + r;
            size_t orow = (size_t)trow(qr) * 128 + h * 32;
            #pragma unroll
            for (int nt = 0; nt < 2; nt++)
                out[orow + nt * 16 + frow] = (bf16_t)O[mt][nt][r];
        }
    }
}

extern "C" void kernel_launch(void* const* d_in, const int* in_sizes, int n_in,
                              void* d_out, int out_size, void* d_ws, size_t ws_size,
                              hipStream_t stream) {
    const float* x       = (const float*)d_in[0];
    const float* a_ln1g  = (const float*)d_in[1];
    const float* a_ln1b  = (const float*)d_in[2];
    const float* a_qkvw  = (const float*)d_in[3];
    const float* a_qkvb  = (const float*)d_in[4];
    const float* a_projw = (const float*)d_in[5];
    const float* a_projb = (const float*)d_in[6];
    const float* a_ln2g  = (const float*)d_in[7];
    const float* a_ln2b  = (const float*)d_in[8];
    const float* a_fc1w  = (const float*)d_in[9];
    const float* a_fc1b  = (const float*)d_in[10];
    const float* a_fc2w  = (const float*)d_in[11];
    const float* a_fc2b  = (const float*)d_in[12];
    const float* b_ln1g  = (const float*)d_in[13];
    const float* b_ln1b  = (const float*)d_in[14];
    const float* b_qkvw  = (const float*)d_in[15];
    const float* b_qkvb  = (const float*)d_in[16];
    const float* b_projw = (const float*)d_in[17];
    const float* b_projb = (const float*)d_in[18];
    const float* b_ln2g  = (const float*)d_in[19];
    const float* b_ln2b  = (const float*)d_in[20];
    const float* b_fc1w  = (const float*)d_in[21];
    const float* b_fc1b  = (const float*)d_in[22];
    const float* b_fc2w  = (const float*)d_in[23];
    const float* b_fc2b  = (const float*)d_in[24];
    const float* mlng    = (const float*)d_in[25];
    const float* mlnb    = (const float*)d_in[26];
    const float* redw    = (const float*)d_in[27];
    float* out = (float*)d_out;

    // workspace layout
    char* p = (char*)d_ws;
    float*  buf_x   = (float*)p;  p += (size_t)NTOK * 128 * 4;   // fp32 residual stream
    bf16_t* buf_ln  = (bf16_t*)p; p += (size_t)NTOK * 128 * 2;   // LN output (bf16)
    bf16_t* buf_big = (bf16_t*)p; p += (size_t)NTOK * 512 * 2;   // qkv+attn | h | merged
    bf16_t* wt      = (bf16_t*)p;                                // transposed weights
    bf16_t* buf_qkv  = buf_big;                       // NTOK*384
    bf16_t* buf_attn = buf_big + (size_t)NTOK * 384;  // NTOK*128
    bf16_t* aqkvT  = wt;
    bf16_t* aprojT = aqkvT  + 384 * 128;
    bf16_t* afc1T  = aprojT + 128 * 128;
    bf16_t* afc2T  = afc1T  + 512 * 128;
    bf16_t* bqkvT  = afc2T  + 128 * 512;
    bf16_t* bprojT = bqkvT  + 384 * 128;
    bf16_t* bfc1T  = bprojT + 128 * 128;
    bf16_t* bfc2T  = bfc1T  + 512 * 128;
    bf16_t* redT   = bfc2T  + 128 * 512;

    // all weight transposes, one dispatch
    TPack tp;
    const float* srcs[9] = {a_qkvw, a_projw, a_fc1w, a_fc2w, b_qkvw, b_projw, b_fc1w, b_fc2w, redw};
    bf16_t* dsts[9] = {aqkvT, aprojT, afc1T, afc2T, bqkvT, bprojT, bfc1T, bfc2T, redT};
    int Ks[9] = {128, 128, 128, 512, 128, 128, 128, 512, 512};
    int Ns[9] = {384, 128, 512, 128, 384, 128, 512, 128, 256};
    for (int i = 0; i < 9; i++) { tp.src[i] = srcs[i]; tp.dst[i] = dsts[i]; tp.K[i] = Ks[i]; tp.N[i] = Ns[i]; }
    kconv_t9<<<dim3(512, 9), dim3(256), 0, stream>>>(tp);

    const dim3 blk256(256);
    const int MG = NTOK / 64;  // 1152

    // ---- block A (W-MSA, shift 0)
    kln128<<<dim3(NTOK / 4), blk256, 0, stream>>>(x, a_ln1g, a_ln1b, buf_ln, NTOK);
    gemm64x128<0><<<dim3(3, MG), blk256, 0, stream>>>(buf_ln, aqkvT, a_qkvb, nullptr, nullptr, buf_qkv, NTOK, 384, 128);
    kattn<<<dim3(1152 * 4), dim3(64), 0, stream>>>(buf_qkv, buf_attn, 0);
    gemm64x128<1><<<dim3(1, MG), blk256, 0, stream>>>(buf_attn, aprojT, a_projb, x, buf_x, nullptr, NTOK, 128, 128);
    kln128<<<dim3(NTOK / 4), blk256, 0, stream>>>(buf_x, a_ln2g, a_ln2b, buf_ln, NTOK);
    gemm64x128<2><<<dim3(4, MG), blk256, 0, stream>>>(buf_ln, afc1T, a_fc1b, nullptr, nullptr, buf_big, NTOK, 512, 128);
    gemm64x128<1><<<dim3(1, MG), blk256, 0, stream>>>(buf_big, afc2T, a_fc2b, buf_x, buf_x, nullptr, NTOK, 128, 512);

    // ---- block B (SW-MSA, shift 4)
    kln128<<<dim3(NTOK / 4), blk256, 0, stream>>>(buf_x, b_ln1g, b_ln1b, buf_ln, NTOK);
    gemm64x128<0><<<dim3(3, MG), blk256, 0, stream>>>(buf_ln, bqkvT, b_qkvb, nullptr, nullptr, buf_qkv, NTOK, 384, 128);
    kattn<<<dim3(1152 * 4), dim3(64), 0, stream>>>(buf_qkv, buf_attn, 4);
    gemm64x128<1><<<dim3(1, MG), blk256, 0, stream>>>(buf_attn, bprojT, b_projb, buf_x, buf_x, nullptr, NTOK, 128, 128);
    kln128<<<dim3(NTOK / 4), blk256, 0, stream>>>(buf_x, b_ln2g, b_ln2b, buf_ln, NTOK);
    gemm64x128<2><<<dim3(4, MG), blk256, 0, stream>>>(buf_ln, bfc1T, b_fc1b, nullptr, nullptr, buf_big, NTOK, 512, 128);
    gemm64x128<1><<<dim3(1, MG), blk256, 0, stream>>>(buf_big, bfc2T, b_fc2b, buf_x, buf_x, nullptr, NTOK, 128, 512);

    // ---- patch merge
    kmergeln<<<dim3(18432 / 4), blk256, 0, stream>>>(buf_x, mlng, mlnb, buf_big);
    gemm64x128<3><<<dim3(2, 288), blk256, 0, stream>>>(buf_big, redT, nullptr, nullptr, out, nullptr, 18432, 256, 512);
}